// Round 11
// baseline (1619.445 us; speedup 1.0000x reference)
//
#include <hip/hip_runtime.h>
#include <stdint.h>

// Attention_48945447306134 on MI355X.
//   GEMM1: QKV = xb @ [wq*C|wk|wv]^T  (wq pre-scaled by softmax_scale*log2e)
//     + fused RoPE epilogue (f32 on-accumulator) for Q/K cols; V written
//       plain, transposed by vtrans_kernel.
//   GEMM: NEW 256x256 8-phase schedule (BK=64, 512 thr / 8 waves, 128KB LDS,
//     counted vmcnt(4) at phases 4/8, per-phase {ds_read || gload_lds ||
//     barrier | MFMA | barrier} interleave, setprio around MFMA). Derived
//     from the m201 template; staging slots placed one phase after each
//     ksub-buffer's last read (WAR-safe), RAW covered by the vmcnt table.
//   Flash attention unchanged from r9/r10 (in-reg P via permlane exchange,
//     counted-vmcnt K/V staging, defer-max, cvt_pk, setprio, linear map).
//   GEMM2: out = attn @ woT (fp32 out), same 8-phase kernel.

typedef unsigned short u16;
typedef __bf16 bf16x8 __attribute__((ext_vector_type(8)));
typedef float  f32x4  __attribute__((ext_vector_type(4)));
typedef unsigned int u32x2 __attribute__((ext_vector_type(2)));

#define GLOAD16(gp, lp)                                                        \
  __builtin_amdgcn_global_load_lds(                                            \
      (const __attribute__((address_space(1))) void*)(gp),                     \
      (__attribute__((address_space(3))) void*)(lp), 16, 0, 0)

__device__ __forceinline__ u16 f2b(float f) {  // RNE f32->bf16
  union { float f; uint32_t u; } v; v.f = f;
  uint32_t r = v.u + 0x7FFFu + ((v.u >> 16) & 1u);
  return (u16)(r >> 16);
}
__device__ __forceinline__ float b2f(u16 h) {
  union { uint32_t u; float f; } v; v.u = ((uint32_t)h) << 16;
  return v.f;
}
// RNE pack via HW instruction
__device__ __forceinline__ uint2 pack4(float a, float b, float c, float d) {
  uint2 r;
  asm("v_cvt_pk_bf16_f32 %0, %1, %2" : "=v"(r.x) : "v"(a), "v"(b));
  asm("v_cvt_pk_bf16_f32 %0, %1, %2" : "=v"(r.y) : "v"(c), "v"(d));
  return r;
}

// block barrier that does NOT drain vmcnt (keeps staging loads in flight).
__device__ __forceinline__ void bar_sync() {
  asm volatile("s_waitcnt lgkmcnt(0)" ::: "memory");
  __builtin_amdgcn_s_barrier();
  asm volatile("" ::: "memory");
}

// ---------------- cast x -> bf16 ----------------
__global__ __launch_bounds__(256) void cast_x_kernel(const float4* __restrict__ in,
                                                     ushort4* __restrict__ out) {
  int i = blockIdx.x * 256 + threadIdx.x;
  float4 v = in[i];
  ushort4 o;
  o.x = f2b(v.x); o.y = f2b(v.y); o.z = f2b(v.z); o.w = f2b(v.w);
  out[i] = o;
}

// ------------- cast + transpose weight: W (KxN f32) -> WT (NxK bf16), * scale -------------
__global__ __launch_bounds__(256) void wtrans_kernel(const float* __restrict__ W,
                                                     u16* __restrict__ WT,
                                                     int K, int N, float scale) {
  __shared__ float t[32][33];
  int n0 = blockIdx.x * 32, k0 = blockIdx.y * 32;
  int tx = threadIdx.x, ty = threadIdx.y;  // 32 x 8
  for (int r = 0; r < 4; r++)
    t[ty + r * 8][tx] = W[(size_t)(k0 + ty + r * 8) * N + n0 + tx];
  __syncthreads();
  for (int r = 0; r < 4; r++)
    WT[(size_t)(n0 + ty + r * 8) * K + k0 + tx] = f2b(t[tx][ty + r * 8] * scale);
}

// ---------------- GEMM: C(MxN) = A(MxK) * BT(NxK)^T, 256^2 8-phase ----------
// 8 waves (2M x 4N), per-wave C = 128x64 (acc[8][4] f32x4). LDS 128KB:
//   A: buf[tp][ks] = [256 rows][32 cols] u16 at (tp*2+ks)*8192; B at +32768.
//   true 16B-chunk c of row r stored at c ^ (r&3); staged via pre-swizzled
//   global source (lane: row += lane>>2, chunk (lane&3)^((lane>>2)&3)).
// Iteration i computes tiles 2i (tp0), 2i+1 (tp1); phase p = (tp, ks, mh):
//   reads af[4] (+bf[4] when mh==0), stages one half-tile, double barrier
//   around 16 MFMA. Staging slots: ph1 A(2i+1)k1, ph2 B(2i+1)k1 (i>0),
//   ph3 A(2i+2)k0, ph4 B(2i+2)k0, ph5 A(2i+2)k1, ph6 B(2i+2)k1,
//   ph7 A(2i+3)k0, ph8 B(2i+3)k0 (i<niter-1). vmcnt(4) at ph4/ph8
//   (vmcnt(0) last iter) -- every staged half lands >=1 vmcnt before read.
#define STG_A(T, KS)                                                           \
  GLOAD16(PA + (size_t)(T) * 64 + (KS) * 32,                                   \
          &SH[(((T) & 1) * 2 + (KS)) * 8192 + ldw]);                           \
  GLOAD16(PA + (size_t)128 * K + (size_t)(T) * 64 + (KS) * 32,                 \
          &SH[(((T) & 1) * 2 + (KS)) * 8192 + ldw + 4096]);

#define STG_B(T, KS)                                                           \
  GLOAD16(PB + (size_t)(T) * 64 + (KS) * 32,                                   \
          &SH[32768 + (((T) & 1) * 2 + (KS)) * 8192 + ldw]);                   \
  GLOAD16(PB + (size_t)128 * K + (size_t)(T) * 64 + (KS) * 32,                 \
          &SH[32768 + (((T) & 1) * 2 + (KS)) * 8192 + ldw + 4096]);

#define PHASE(TP, KS, MH, STAGE_STMT, WAIT_STMT)                               \
  {                                                                            \
    bf16x8 af[4];                                                              \
    const int ao = ((TP) * 2 + (KS)) * 8192;                                   \
    for (int q = 0; q < 4; q++)                                                \
      af[q] = *(const bf16x8*)&SH[ao + aBase + ((MH) * 4 + q) * 512];          \
    if ((MH) == 0)                                                             \
      for (int q = 0; q < 4; q++)                                              \
        bf[q] = *(const bf16x8*)&SH[32768 + ao + bBase + q * 512];             \
    STAGE_STMT;                                                                \
    __builtin_amdgcn_s_barrier();                                              \
    asm volatile("s_waitcnt lgkmcnt(0)" ::: "memory");                         \
    __builtin_amdgcn_s_setprio(1);                                             \
    for (int q = 0; q < 4; q++)                                                \
      for (int nr = 0; nr < 4; nr++)                                           \
        acc[(MH) * 4 + q][nr] = __builtin_amdgcn_mfma_f32_16x16x32_bf16(       \
            af[q], bf[nr], acc[(MH) * 4 + q][nr], 0, 0, 0);                    \
    __builtin_amdgcn_s_setprio(0);                                             \
    WAIT_STMT;                                                                 \
    __builtin_amdgcn_s_barrier();                                              \
    asm volatile("" ::: "memory");                                             \
  }

template <bool BF16OUT>
__global__ __launch_bounds__(512, 1) void gemm_bt_kernel(const u16* __restrict__ A,
                                                         const u16* __restrict__ BT,
                                                         void* __restrict__ Cv,
                                                         int K, int N,
                                                         const float* __restrict__ cs,
                                                         const float* __restrict__ sn) {
  __shared__ u16 SH[65536];  // 128 KB
  const int tid = threadIdx.x;
  const int wave = tid >> 6, lane = tid & 63;
  const int quad = lane >> 4, l16 = lane & 15;
  const int wr = wave >> 2, wc = wave & 3;

  // XCD-aware bijective block swizzle (nwg % 8 == 0 for both call sites)
  const int nbx = gridDim.x;
  const int nwg = nbx * gridDim.y;
  const int d = blockIdx.x + blockIdx.y * nbx;
  const int w = (d & 7) * (nwg >> 3) + (d >> 3);
  const size_t m0 = (size_t)(w / nbx) * 256, n0 = (size_t)(w % nbx) * 256;

  f32x4 acc[8][4] = {};

  const int csw = ((lane & 3) ^ ((lane >> 2) & 3)) * 8;
  const u16* PA = A + (m0 + wave * 16 + (lane >> 2)) * (size_t)K + csw;
  const u16* PB = BT + (n0 + wave * 16 + (lane >> 2)) * (size_t)K + csw;
  const int slot8 = (quad ^ (l16 & 3)) << 3;
  const int aBase = (wr * 128 + l16) * 32 + slot8;
  const int bBase = (wc * 64 + l16) * 32 + slot8;
  const int ldw = wave * 512;

  const int niter = K >> 7;  // pairs of BK=64 tiles (K=2048 -> 16)

  // prologue: stage tiles 0 and 1 completely, drain
  STG_A(0, 0) STG_A(0, 1) STG_B(0, 0) STG_B(0, 1)
  STG_A(1, 0) STG_A(1, 1) STG_B(1, 0) STG_B(1, 1)
  __syncthreads();

  for (int i = 0; i < niter; i++) {
    const int t0 = 2 * i;
    const bool nx = (i + 1 < niter);
    const bool p0 = (i > 0);
    bf16x8 bf[4];
    PHASE(0, 0, 0, if (p0) { STG_A(t0 + 1, 1) }, )
    PHASE(0, 0, 1, if (p0) { STG_B(t0 + 1, 1) }, )
    PHASE(0, 1, 0, if (nx) { STG_A(t0 + 2, 0) }, )
    PHASE(0, 1, 1, if (nx) { STG_B(t0 + 2, 0) },
          if (nx) { asm volatile("s_waitcnt vmcnt(4)" ::: "memory"); }
          else    { asm volatile("s_waitcnt vmcnt(0)" ::: "memory"); })
    PHASE(1, 0, 0, if (nx) { STG_A(t0 + 2, 1) }, )
    PHASE(1, 0, 1, if (nx) { STG_B(t0 + 2, 1) }, )
    PHASE(1, 1, 0, if (nx) { STG_A(t0 + 3, 0) }, )
    PHASE(1, 1, 1, if (nx) { STG_B(t0 + 3, 0) },
          if (nx) { asm volatile("s_waitcnt vmcnt(4)" ::: "memory"); }
          else    { asm volatile("s_waitcnt vmcnt(0)" ::: "memory"); })
  }

  // ---- epilogue ----
  if constexpr (BF16OUT) {
    if ((int)n0 >= 2560) {
      // V block: plain bf16 store (vtrans_kernel transposes afterwards)
      for (int mr = 0; mr < 8; mr++)
        for (int nr = 0; nr < 4; nr++)
          for (int r = 0; r < 4; r++) {
            size_t row = m0 + wr * 128 + mr * 16 + quad * 4 + r;
            size_t col = n0 + wc * 64 + nr * 16 + l16;
            ((u16*)Cv)[row * N + col] = f2b(acc[mr][nr][r]);
          }
    } else {
      // Q/K block: RoPE in f32 on accumulator (pair = lane l16^1), bf16 store
      for (int mr = 0; mr < 8; mr++)
        for (int nr = 0; nr < 4; nr++) {
          int col = (int)n0 + wc * 64 + nr * 16 + l16;
          int ii = (col & 127) >> 1;
          bool odd = (col & 1) != 0;
          for (int r = 0; r < 4; r++) {
            int row = (int)m0 + wr * 128 + mr * 16 + quad * 4 + r;
            int s = row & 2047;
            float v = acc[mr][nr][r];
            float pv = __shfl_xor(v, 1, 64);
            float c_ = cs[(size_t)s * 64 + ii];
            float s_ = sn[(size_t)s * 64 + ii];
            float out = odd ? (pv * s_ + v * c_) : (v * c_ - pv * s_);
            ((u16*)Cv)[(size_t)row * N + col] = f2b(out);
          }
        }
    }
  } else {
    for (int mr = 0; mr < 8; mr++)
      for (int nr = 0; nr < 4; nr++)
        for (int r = 0; r < 4; r++) {
          size_t row = m0 + wr * 128 + mr * 16 + quad * 4 + r;
          size_t col = n0 + wc * 64 + nr * 16 + l16;
          ((float*)Cv)[row * N + col] = acc[mr][nr][r];
        }
  }
}

// ---------------- V transpose ----------------
__global__ __launch_bounds__(256) void vtrans_kernel(const u16* __restrict__ QKV,
                                                     u16* __restrict__ Vt) {
  __shared__ u16 t[32][33];
  int b = blockIdx.z >> 2, hk = blockIdx.z & 3;
  int s0 = blockIdx.x * 32, d0 = blockIdx.y * 32;
  int tx = threadIdx.x, ty = threadIdx.y;
  const u16* src = QKV + (size_t)(b * 2048 + s0) * 3072 + 2560 + hk * 128 + d0;
  for (int r = 0; r < 4; r++)
    t[ty + r * 8][tx] = src[(size_t)(ty + r * 8) * 3072 + tx];
  __syncthreads();
  u16* dst = Vt + ((size_t)((b * 4 + hk) * 128 + d0)) * 2048 + s0;
  for (int r = 0; r < 4; r++)
    dst[(size_t)(ty + r * 8) * 2048 + tx] = t[tx][ty + r * 8];
}

// ---------------- flash attention (transposed algebra, P in registers) ------
// grid (qt=16, h=16, b=4), 256 threads = 4 waves, 32 q-rows/wave. Linear
// block mapping. Per iter kt:
//   [top] if kt>0: issue V_kt gload_lds
//   QK^T -> BARRIER_A -> issue K_{kt+1} gload_lds
//   softmax + exp->bf16 pack -> permlane32_swap/xor16 exchange -> pf (in-reg)
//   BARRIER_B: vmcnt(8) (drain V_kt, keep K flying)
//   PV -> BARRIER_END: vmcnt(0)
__global__ __launch_bounds__(256, 2) void attn_kernel(const u16* __restrict__ QKV,
                                                      const u16* __restrict__ Vt,
                                                      u16* __restrict__ AO) {
  __shared__ u16 KP[128 * 128];
  __shared__ u16 Vls[128 * 128];
  const int tid = threadIdx.x;
  const int wave = tid >> 6, lane = tid & 63;
  const int quad = lane >> 4, l16 = lane & 15;
  const int qt = blockIdx.x, h = blockIdx.y, b = blockIdx.z;
  const int hk = h >> 2;
  const int sw = l16 & 7;  // row-dependent swizzle key for this lane's rows

  // Q fragments (B-operand: n=q=l16, k=d)
  bf16x8 qf[2][4];
  {
    const u16* Qb = QKV + (size_t)(b * 2048 + qt * 128 + wave * 32) * 3072 + h * 128;
    for (int qb = 0; qb < 2; qb++)
      for (int ki = 0; ki < 4; ki++)
        qf[qb][ki] = *(const bf16x8*)(Qb + (size_t)(qb * 16 + l16) * 3072 + ki * 32 + quad * 8);
  }
  f32x4 o[8][2] = {};            // O^T: [db][qb], col=q(l16), row=d(quad*4+r)
  float m_[2] = {-1e30f, -1e30f}, l_[2] = {0.f, 0.f};

  const u16* Kg0 = QKV + 2048 + hk * 128;
  const u16* Vg0 = Vt + (size_t)((b * 4 + hk) * 128) * 2048;
  const int r4 = lane >> 4, c16 = lane & 15;

  auto stageK = [&](int t) {
    const u16* Kg = Kg0 + (size_t)(b * 2048 + t * 128) * 3072;
    for (int i = 0; i < 8; i++) {
      int grp = i * 4 + wave;
      int row = grp * 4 + r4;
      int ch = c16 ^ (row & 7);
      GLOAD16(Kg + (size_t)row * 3072 + ch * 8, &KP[grp * 512]);
    }
  };
  auto stageV = [&](int t) {
    const u16* Vg = Vg0 + t * 128;
    for (int i = 0; i < 8; i++) {
      int grp = i * 4 + wave;
      int row = grp * 4 + r4;
      int ch = c16 ^ (row & 7);
      GLOAD16(Vg + (size_t)row * 2048 + ch * 8, &Vls[grp * 512]);
    }
  };

  // ---- prologue: stage tile 0 (drained by syncthreads)
  stageK(0);
  stageV(0);
  __syncthreads();

  for (int kt = 0; kt < 16; kt++) {
    if (kt > 0) stageV(kt);  // in flight until BARRIER_B

    // S^T = K Q^T : A = K-frag (m=key), B = Q-frag (n=q)
    f32x4 s[8][2];
    for (int kb = 0; kb < 8; kb++) {
      bf16x8 kf[4];
      int a0 = (kb * 16 + l16) * 128 + ((quad ^ sw) << 3);
      for (int ki = 0; ki < 4; ki++)
        kf[ki] = *(const bf16x8*)&KP[a0 ^ (ki * 32)];
      __builtin_amdgcn_s_setprio(1);
      for (int qb = 0; qb < 2; qb++) {
        f32x4 a = {0.f, 0.f, 0.f, 0.f};
        for (int ki = 0; ki < 4; ki++)
          a = __builtin_amdgcn_mfma_f32_16x16x32_bf16(kf[ki], qf[qb][ki], a, 0, 0, 0);
        s[kb][qb] = a;
      }
      __builtin_amdgcn_s_setprio(0);
    }

    bar_sync();  // BARRIER_A: all waves' K reads done
    if (kt < 15) stageK(kt + 1);  // in flight until BARRIER_END

    // online softmax per q (q = qb*16 + l16); scores pre-scaled by C*log2e.
    bf16x8 pf[2][4];
    float alch[2];
    for (int qb = 0; qb < 2; qb++) {
      float mk[8];
#pragma unroll
      for (int kb = 0; kb < 8; kb++)
        mk[kb] = fmaxf(fmaxf(s[kb][qb][0], s[kb][qb][1]),
                       fmaxf(s[kb][qb][2], s[kb][qb][3]));
      float mx = fmaxf(fmaxf(fmaxf(mk[0], mk[1]), fmaxf(mk[2], mk[3])),
                       fmaxf(fmaxf(mk[4], mk[5]), fmaxf(mk[6], mk[7])));
      mx = fmaxf(mx, __shfl_xor(mx, 16, 64));
      mx = fmaxf(mx, __shfl_xor(mx, 32, 64));
      float mn = m_[qb], al = 1.0f;
      if (!__all(mx <= m_[qb] + 8.0f)) {
        mn = fmaxf(m_[qb], mx);
        al = exp2f(m_[qb] - mn);
        m_[qb] = mn;
      }
      alch[qb] = al;
      uint2 u[8];
      float rs = 0.f;
#pragma unroll
      for (int kb = 0; kb < 8; kb++) {
        float p0 = exp2f(s[kb][qb][0] - mn), p1 = exp2f(s[kb][qb][1] - mn);
        float p2 = exp2f(s[kb][qb][2] - mn), p3 = exp2f(s[kb][qb][3] - mn);
        u[kb] = pack4(p0, p1, p2, p3);
        rs += (p0 + p1) + (p2 + p3);
      }
      rs += __shfl_xor(rs, 16, 64);
      rs += __shfl_xor(rs, 32, 64);
      l_[qb] = l_[qb] * al + rs;
      // exchange: pf[qb][ki] = P[q=l16-row][keys ki*32 + quad*8 + 0..7].
      const bool qo = (quad & 1) != 0;
#pragma unroll
      for (int ki = 0; ki < 4; ki++) {
        u32x2 r1 = __builtin_amdgcn_permlane32_swap(u[2 * ki].x, u[2 * ki + 1].x, false, false);
        u32x2 r2 = __builtin_amdgcn_permlane32_swap(u[2 * ki].y, u[2 * ki + 1].y, false, false);
        uint32_t t1b = (uint32_t)__shfl_xor((int)r1[1], 16, 64);
        uint32_t t1a = (uint32_t)__shfl_xor((int)r1[0], 16, 64);
        uint32_t t2b = (uint32_t)__shfl_xor((int)r2[1], 16, 64);
        uint32_t t2a = (uint32_t)__shfl_xor((int)r2[0], 16, 64);
        uint4 d;
        d.x = qo ? t1b : (uint32_t)r1[0];
        d.y = qo ? t2b : (uint32_t)r2[0];
        d.z = qo ? (uint32_t)r1[1] : t1a;
        d.w = qo ? (uint32_t)r2[1] : t2a;
        pf[qb][ki] = *(bf16x8*)&d;
      }
    }
    if (alch[0] != 1.0f || alch[1] != 1.0f) {
#pragma unroll
      for (int db = 0; db < 8; db++) {
        o[db][0] *= alch[0];
        o[db][1] *= alch[1];
      }
    }

    // BARRIER_B: drain V_kt (8 older loads; the 8 K_{kt+1} stay flying)
    if (kt == 15) asm volatile("s_waitcnt vmcnt(0)" ::: "memory");
    else          asm volatile("s_waitcnt vmcnt(8)" ::: "memory");
    bar_sync();

    // O^T += V^T P^T : A = V-frag (m=d), B = pf (n=q, in registers)
    for (int db = 0; db < 8; db++) {
      bf16x8 vf[4];
      int a0 = (db * 16 + l16) * 128 + ((quad ^ sw) << 3);
      for (int ki = 0; ki < 4; ki++)
        vf[ki] = *(const bf16x8*)&Vls[a0 ^ (ki * 32)];
      __builtin_amdgcn_s_setprio(1);
      for (int qb = 0; qb < 2; qb++)
        for (int ki = 0; ki < 4; ki++)
          o[db][qb] = __builtin_amdgcn_mfma_f32_16x16x32_bf16(vf[ki], pf[qb][ki], o[db][qb], 0, 0, 0);
      __builtin_amdgcn_s_setprio(0);
    }

    // BARRIER_END: K_{kt+1} landed (covered by softmax+PV); Vls free after
    asm volatile("s_waitcnt vmcnt(0)" ::: "memory");
    bar_sync();
  }

  // epilogue: O^T/l -> LDS [q][d] packed b64 -> coalesced global store
  float inv[2] = {1.0f / l_[0], 1.0f / l_[1]};
  for (int qb = 0; qb < 2; qb++) {
    int rq = wave * 32 + qb * 16 + l16;
    for (int db = 0; db < 8; db++) {
      int ch = (db * 2 + (quad >> 1)) ^ sw;
      uint2 pv = pack4(o[db][qb][0] * inv[qb], o[db][qb][1] * inv[qb],
                       o[db][qb][2] * inv[qb], o[db][qb][3] * inv[qb]);
      *(uint2*)&KP[rq * 128 + (ch << 3) + (quad & 1) * 4] = pv;
    }
  }
  __syncthreads();
  u16* Ab = AO + (size_t)(b * 2048 + qt * 128) * 2048 + h * 128;
  for (int i = 0; i < 8; i++) {
    int row = i * 16 + (tid >> 4);
    int seg = tid & 15;
    int pc = seg ^ (row & 7);
    *(uint4*)(Ab + (size_t)row * 2048 + seg * 8) = *(const uint4*)&KP[row * 128 + pc * 8];
  }
}

// ---------------- launch ----------------
extern "C" void kernel_launch(void* const* d_in, const int* in_sizes, int n_in,
                              void* d_out, int out_size, void* d_ws, size_t ws_size,
                              hipStream_t stream) {
  (void)in_sizes; (void)n_in; (void)out_size; (void)ws_size;
  const float* x    = (const float*)d_in[0];
  const float* fcos = (const float*)d_in[1];
  const float* fsin = (const float*)d_in[2];
  const float* wq   = (const float*)d_in[3];
  const float* wk   = (const float*)d_in[4];
  const float* wv   = (const float*)d_in[5];
  const float* wo   = (const float*)d_in[6];

  char* w = (char*)d_ws;
  u16* xb  = (u16*)w;                               // 8192x2048 bf16, reused as attn_out
  u16* wT  = (u16*)(w + 33554432);                  // 3072x2048 bf16
  u16* woT = (u16*)(w + 33554432 + 12582912);       // 2048x2048 bf16
  u16* QKV = (u16*)(w + 33554432 + 12582912 + 8388608);            // 8192x3072 bf16
  u16* Vt  = (u16*)(w + 33554432 + 12582912 + 8388608 + 50331648); // 16x128x2048 bf16
  u16* AO  = xb;

  const float C = 0.08838834764831845f * 1.44269504088896340f;  // 1/sqrt(128)*log2(e)

  cast_x_kernel<<<16384, 256, 0, stream>>>((const float4*)x, (ushort4*)xb);
  wtrans_kernel<<<dim3(64, 64), dim3(32, 8), 0, stream>>>(wq, wT, 2048, 2048, C);
  wtrans_kernel<<<dim3(16, 64), dim3(32, 8), 0, stream>>>(wk, wT + (size_t)2048 * 2048, 2048, 512, 1.0f);
  wtrans_kernel<<<dim3(16, 64), dim3(32, 8), 0, stream>>>(wv, wT + (size_t)2560 * 2048, 2048, 512, 1.0f);
  wtrans_kernel<<<dim3(64, 64), dim3(32, 8), 0, stream>>>(wo, woT, 2048, 2048, 1.0f);

  // GEMM1 (256^2 8-phase) with fused RoPE epilogue; V plain -> vtrans
  gemm_bt_kernel<true><<<dim3(12, 32), 512, 0, stream>>>(xb, wT, QKV, 2048, 3072,
                                                         fcos, fsin);
  vtrans_kernel<<<dim3(64, 4, 16), dim3(32, 8), 0, stream>>>(QKV, Vt);
  attn_kernel<<<dim3(16, 16, 4), 256, 0, stream>>>(QKV, Vt, AO);
  gemm_bt_kernel<false><<<dim3(8, 32), 512, 0, stream>>>(AO, woT, (float*)d_out, 2048, 2048,
                                                         nullptr, nullptr);
}

// Round 12
// 554.909 us; speedup vs baseline: 2.9184x; 2.9184x over previous
//
#include <hip/hip_runtime.h>
#include <stdint.h>

// Attention_48945447306134 on MI355X.
//   GEMM1: QKV = xb @ [wq*C|wk|wv]^T  (wq pre-scaled by softmax_scale*log2e)
//     + fused RoPE epilogue (f32 on-accumulator) for Q/K cols; V written
//       plain, transposed by vtrans_kernel.
//   GEMM: 256x256 8-phase schedule (BK=64, 512 thr / 8 waves, 128KB LDS,
//     counted vmcnt(4) at phases 4/8). r11 ran this with acc SPILLED to
//     scratch (VGPR=108, WRITE 6.4GB): the rolled epilogue loops made
//     acc[mr][nr][r] runtime-indexed (rule #20). This rev forces static
//     indexing: _Pragma unroll in PHASE, #pragma unroll on epilogue loops,
//     #pragma unroll 1 on the K-iteration loop (code-size bound).
//   Flash attention unchanged from r9/r10.
//   GEMM2: out = attn @ woT (fp32 out), same 8-phase kernel.

typedef unsigned short u16;
typedef __bf16 bf16x8 __attribute__((ext_vector_type(8)));
typedef float  f32x4  __attribute__((ext_vector_type(4)));
typedef unsigned int u32x2 __attribute__((ext_vector_type(2)));

#define GLOAD16(gp, lp)                                                        \
  __builtin_amdgcn_global_load_lds(                                            \
      (const __attribute__((address_space(1))) void*)(gp),                     \
      (__attribute__((address_space(3))) void*)(lp), 16, 0, 0)

__device__ __forceinline__ u16 f2b(float f) {  // RNE f32->bf16
  union { float f; uint32_t u; } v; v.f = f;
  uint32_t r = v.u + 0x7FFFu + ((v.u >> 16) & 1u);
  return (u16)(r >> 16);
}
__device__ __forceinline__ float b2f(u16 h) {
  union { uint32_t u; float f; } v; v.u = ((uint32_t)h) << 16;
  return v.f;
}
// RNE pack via HW instruction
__device__ __forceinline__ uint2 pack4(float a, float b, float c, float d) {
  uint2 r;
  asm("v_cvt_pk_bf16_f32 %0, %1, %2" : "=v"(r.x) : "v"(a), "v"(b));
  asm("v_cvt_pk_bf16_f32 %0, %1, %2" : "=v"(r.y) : "v"(c), "v"(d));
  return r;
}

// block barrier that does NOT drain vmcnt (keeps staging loads in flight).
__device__ __forceinline__ void bar_sync() {
  asm volatile("s_waitcnt lgkmcnt(0)" ::: "memory");
  __builtin_amdgcn_s_barrier();
  asm volatile("" ::: "memory");
}

// ---------------- cast x -> bf16 ----------------
__global__ __launch_bounds__(256) void cast_x_kernel(const float4* __restrict__ in,
                                                     ushort4* __restrict__ out) {
  int i = blockIdx.x * 256 + threadIdx.x;
  float4 v = in[i];
  ushort4 o;
  o.x = f2b(v.x); o.y = f2b(v.y); o.z = f2b(v.z); o.w = f2b(v.w);
  out[i] = o;
}

// ------------- cast + transpose weight: W (KxN f32) -> WT (NxK bf16), * scale -------------
__global__ __launch_bounds__(256) void wtrans_kernel(const float* __restrict__ W,
                                                     u16* __restrict__ WT,
                                                     int K, int N, float scale) {
  __shared__ float t[32][33];
  int n0 = blockIdx.x * 32, k0 = blockIdx.y * 32;
  int tx = threadIdx.x, ty = threadIdx.y;  // 32 x 8
  for (int r = 0; r < 4; r++)
    t[ty + r * 8][tx] = W[(size_t)(k0 + ty + r * 8) * N + n0 + tx];
  __syncthreads();
  for (int r = 0; r < 4; r++)
    WT[(size_t)(n0 + ty + r * 8) * K + k0 + tx] = f2b(t[tx][ty + r * 8] * scale);
}

// ---------------- GEMM: C(MxN) = A(MxK) * BT(NxK)^T, 256^2 8-phase ----------
// 8 waves (2M x 4N), per-wave C = 128x64 (acc[8][4] f32x4 -- MUST stay in
// registers: every index below is compile-time via forced unrolls).
// LDS 128KB: A buf[tp][ks] = [256 r][32 c] u16 at (tp*2+ks)*8192; B at
// +32768. True chunk c of row r stored at c ^ (r&3); staged via
// pre-swizzled global source. Iteration i computes tiles 2i, 2i+1; phase
// (tp,ks,mh) reads af[4] (+bf[4] at mh0), stages one half-tile, double
// barrier around 16 MFMA. vmcnt(4) at ph4/ph8 (vmcnt(0) last iter):
// verified RAW table -- steady state 4 outstanding at iter entry, 12 at
// each wait, retired halves are exactly those read next.
#define STG_A(T, KS)                                                           \
  GLOAD16(PA + (size_t)(T) * 64 + (KS) * 32,                                   \
          &SH[(((T) & 1) * 2 + (KS)) * 8192 + ldw]);                           \
  GLOAD16(PA + (size_t)128 * K + (size_t)(T) * 64 + (KS) * 32,                 \
          &SH[(((T) & 1) * 2 + (KS)) * 8192 + ldw + 4096]);

#define STG_B(T, KS)                                                           \
  GLOAD16(PB + (size_t)(T) * 64 + (KS) * 32,                                   \
          &SH[32768 + (((T) & 1) * 2 + (KS)) * 8192 + ldw]);                   \
  GLOAD16(PB + (size_t)128 * K + (size_t)(T) * 64 + (KS) * 32,                 \
          &SH[32768 + (((T) & 1) * 2 + (KS)) * 8192 + ldw + 4096]);

#define PHASE(TP, KS, MH, STAGE_STMT, WAIT_STMT)                               \
  {                                                                            \
    bf16x8 af[4];                                                              \
    const int ao = ((TP) * 2 + (KS)) * 8192;                                   \
    _Pragma("unroll")                                                          \
    for (int q = 0; q < 4; q++)                                                \
      af[q] = *(const bf16x8*)&SH[ao + aBase + ((MH) * 4 + q) * 512];          \
    if ((MH) == 0) {                                                           \
      _Pragma("unroll")                                                        \
      for (int q = 0; q < 4; q++)                                              \
        bf[q] = *(const bf16x8*)&SH[32768 + ao + bBase + q * 512];             \
    }                                                                          \
    STAGE_STMT;                                                                \
    __builtin_amdgcn_s_barrier();                                              \
    asm volatile("s_waitcnt lgkmcnt(0)" ::: "memory");                         \
    __builtin_amdgcn_s_setprio(1);                                             \
    _Pragma("unroll")                                                          \
    for (int q = 0; q < 4; q++) {                                              \
      _Pragma("unroll")                                                        \
      for (int nr = 0; nr < 4; nr++)                                           \
        acc[(MH) * 4 + q][nr] = __builtin_amdgcn_mfma_f32_16x16x32_bf16(       \
            af[q], bf[nr], acc[(MH) * 4 + q][nr], 0, 0, 0);                    \
    }                                                                          \
    __builtin_amdgcn_s_setprio(0);                                             \
    WAIT_STMT;                                                                 \
    __builtin_amdgcn_s_barrier();                                              \
    asm volatile("" ::: "memory");                                             \
  }

template <bool BF16OUT>
__global__ __launch_bounds__(512, 1) void gemm_bt_kernel(const u16* __restrict__ A,
                                                         const u16* __restrict__ BT,
                                                         void* __restrict__ Cv,
                                                         int K, int N,
                                                         const float* __restrict__ cs,
                                                         const float* __restrict__ sn) {
  __shared__ u16 SH[65536];  // 128 KB
  const int tid = threadIdx.x;
  const int wave = tid >> 6, lane = tid & 63;
  const int quad = lane >> 4, l16 = lane & 15;
  const int wr = wave >> 2, wc = wave & 3;

  // XCD-aware bijective block swizzle (nwg % 8 == 0 for both call sites)
  const int nbx = gridDim.x;
  const int nwg = nbx * gridDim.y;
  const int d = blockIdx.x + blockIdx.y * nbx;
  const int w = (d & 7) * (nwg >> 3) + (d >> 3);
  const size_t m0 = (size_t)(w / nbx) * 256, n0 = (size_t)(w % nbx) * 256;

  f32x4 acc[8][4] = {};

  const int csw = ((lane & 3) ^ ((lane >> 2) & 3)) * 8;
  const u16* PA = A + (m0 + wave * 16 + (lane >> 2)) * (size_t)K + csw;
  const u16* PB = BT + (n0 + wave * 16 + (lane >> 2)) * (size_t)K + csw;
  const int slot8 = (quad ^ (l16 & 3)) << 3;
  const int aBase = (wr * 128 + l16) * 32 + slot8;
  const int bBase = (wc * 64 + l16) * 32 + slot8;
  const int ldw = wave * 512;

  const int niter = K >> 7;  // pairs of BK=64 tiles (K=2048 -> 16)

  // prologue: stage tiles 0 and 1 completely, drain
  STG_A(0, 0) STG_A(0, 1) STG_B(0, 0) STG_B(0, 1)
  STG_A(1, 0) STG_A(1, 1) STG_B(1, 0) STG_B(1, 1)
  __syncthreads();

#pragma unroll 1
  for (int i = 0; i < niter; i++) {
    const int t0 = 2 * i;
    const bool nx = (i + 1 < niter);
    const bool p0 = (i > 0);
    bf16x8 bf[4];
    PHASE(0, 0, 0, if (p0) { STG_A(t0 + 1, 1) }, )
    PHASE(0, 0, 1, if (p0) { STG_B(t0 + 1, 1) }, )
    PHASE(0, 1, 0, if (nx) { STG_A(t0 + 2, 0) }, )
    PHASE(0, 1, 1, if (nx) { STG_B(t0 + 2, 0) },
          if (nx) { asm volatile("s_waitcnt vmcnt(4)" ::: "memory"); }
          else    { asm volatile("s_waitcnt vmcnt(0)" ::: "memory"); })
    PHASE(1, 0, 0, if (nx) { STG_A(t0 + 2, 1) }, )
    PHASE(1, 0, 1, if (nx) { STG_B(t0 + 2, 1) }, )
    PHASE(1, 1, 0, if (nx) { STG_A(t0 + 3, 0) }, )
    PHASE(1, 1, 1, if (nx) { STG_B(t0 + 3, 0) },
          if (nx) { asm volatile("s_waitcnt vmcnt(4)" ::: "memory"); }
          else    { asm volatile("s_waitcnt vmcnt(0)" ::: "memory"); })
  }

  // ---- epilogue (all loops unrolled: acc must stay register-indexed) ----
  if constexpr (BF16OUT) {
    if ((int)n0 >= 2560) {
      // V block: plain bf16 store (vtrans_kernel transposes afterwards)
#pragma unroll
      for (int mr = 0; mr < 8; mr++)
#pragma unroll
        for (int nr = 0; nr < 4; nr++)
#pragma unroll
          for (int r = 0; r < 4; r++) {
            size_t row = m0 + wr * 128 + mr * 16 + quad * 4 + r;
            size_t col = n0 + wc * 64 + nr * 16 + l16;
            ((u16*)Cv)[row * N + col] = f2b(acc[mr][nr][r]);
          }
    } else {
      // Q/K block: RoPE in f32 on accumulator (pair = lane l16^1), bf16 store
#pragma unroll
      for (int mr = 0; mr < 8; mr++)
#pragma unroll
        for (int nr = 0; nr < 4; nr++) {
          int col = (int)n0 + wc * 64 + nr * 16 + l16;
          int ii = (col & 127) >> 1;
          bool odd = (col & 1) != 0;
#pragma unroll
          for (int r = 0; r < 4; r++) {
            int row = (int)m0 + wr * 128 + mr * 16 + quad * 4 + r;
            int s = row & 2047;
            float v = acc[mr][nr][r];
            float pv = __shfl_xor(v, 1, 64);
            float c_ = cs[(size_t)s * 64 + ii];
            float s_ = sn[(size_t)s * 64 + ii];
            float out = odd ? (pv * s_ + v * c_) : (v * c_ - pv * s_);
            ((u16*)Cv)[(size_t)row * N + col] = f2b(out);
          }
        }
    }
  } else {
#pragma unroll
    for (int mr = 0; mr < 8; mr++)
#pragma unroll
      for (int nr = 0; nr < 4; nr++)
#pragma unroll
        for (int r = 0; r < 4; r++) {
          size_t row = m0 + wr * 128 + mr * 16 + quad * 4 + r;
          size_t col = n0 + wc * 64 + nr * 16 + l16;
          ((float*)Cv)[row * N + col] = acc[mr][nr][r];
        }
  }
}

// ---------------- V transpose ----------------
__global__ __launch_bounds__(256) void vtrans_kernel(const u16* __restrict__ QKV,
                                                     u16* __restrict__ Vt) {
  __shared__ u16 t[32][33];
  int b = blockIdx.z >> 2, hk = blockIdx.z & 3;
  int s0 = blockIdx.x * 32, d0 = blockIdx.y * 32;
  int tx = threadIdx.x, ty = threadIdx.y;
  const u16* src = QKV + (size_t)(b * 2048 + s0) * 3072 + 2560 + hk * 128 + d0;
  for (int r = 0; r < 4; r++)
    t[ty + r * 8][tx] = src[(size_t)(ty + r * 8) * 3072 + tx];
  __syncthreads();
  u16* dst = Vt + ((size_t)((b * 4 + hk) * 128 + d0)) * 2048 + s0;
  for (int r = 0; r < 4; r++)
    dst[(size_t)(ty + r * 8) * 2048 + tx] = t[tx][ty + r * 8];
}

// ---------------- flash attention (transposed algebra, P in registers) ------
// grid (qt=16, h=16, b=4), 256 threads = 4 waves, 32 q-rows/wave. Linear
// block mapping. Per iter kt:
//   [top] if kt>0: issue V_kt gload_lds
//   QK^T -> BARRIER_A -> issue K_{kt+1} gload_lds
//   softmax + exp->bf16 pack -> permlane32_swap/xor16 exchange -> pf (in-reg)
//   BARRIER_B: vmcnt(8) (drain V_kt, keep K flying)
//   PV -> BARRIER_END: vmcnt(0)
__global__ __launch_bounds__(256, 2) void attn_kernel(const u16* __restrict__ QKV,
                                                      const u16* __restrict__ Vt,
                                                      u16* __restrict__ AO) {
  __shared__ u16 KP[128 * 128];
  __shared__ u16 Vls[128 * 128];
  const int tid = threadIdx.x;
  const int wave = tid >> 6, lane = tid & 63;
  const int quad = lane >> 4, l16 = lane & 15;
  const int qt = blockIdx.x, h = blockIdx.y, b = blockIdx.z;
  const int hk = h >> 2;
  const int sw = l16 & 7;  // row-dependent swizzle key for this lane's rows

  // Q fragments (B-operand: n=q=l16, k=d)
  bf16x8 qf[2][4];
  {
    const u16* Qb = QKV + (size_t)(b * 2048 + qt * 128 + wave * 32) * 3072 + h * 128;
    for (int qb = 0; qb < 2; qb++)
      for (int ki = 0; ki < 4; ki++)
        qf[qb][ki] = *(const bf16x8*)(Qb + (size_t)(qb * 16 + l16) * 3072 + ki * 32 + quad * 8);
  }
  f32x4 o[8][2] = {};            // O^T: [db][qb], col=q(l16), row=d(quad*4+r)
  float m_[2] = {-1e30f, -1e30f}, l_[2] = {0.f, 0.f};

  const u16* Kg0 = QKV + 2048 + hk * 128;
  const u16* Vg0 = Vt + (size_t)((b * 4 + hk) * 128) * 2048;
  const int r4 = lane >> 4, c16 = lane & 15;

  auto stageK = [&](int t) {
    const u16* Kg = Kg0 + (size_t)(b * 2048 + t * 128) * 3072;
    for (int i = 0; i < 8; i++) {
      int grp = i * 4 + wave;
      int row = grp * 4 + r4;
      int ch = c16 ^ (row & 7);
      GLOAD16(Kg + (size_t)row * 3072 + ch * 8, &KP[grp * 512]);
    }
  };
  auto stageV = [&](int t) {
    const u16* Vg = Vg0 + t * 128;
    for (int i = 0; i < 8; i++) {
      int grp = i * 4 + wave;
      int row = grp * 4 + r4;
      int ch = c16 ^ (row & 7);
      GLOAD16(Vg + (size_t)row * 2048 + ch * 8, &Vls[grp * 512]);
    }
  };

  // ---- prologue: stage tile 0 (drained by syncthreads)
  stageK(0);
  stageV(0);
  __syncthreads();

  for (int kt = 0; kt < 16; kt++) {
    if (kt > 0) stageV(kt);  // in flight until BARRIER_B

    // S^T = K Q^T : A = K-frag (m=key), B = Q-frag (n=q)
    f32x4 s[8][2];
    for (int kb = 0; kb < 8; kb++) {
      bf16x8 kf[4];
      int a0 = (kb * 16 + l16) * 128 + ((quad ^ sw) << 3);
      for (int ki = 0; ki < 4; ki++)
        kf[ki] = *(const bf16x8*)&KP[a0 ^ (ki * 32)];
      __builtin_amdgcn_s_setprio(1);
      for (int qb = 0; qb < 2; qb++) {
        f32x4 a = {0.f, 0.f, 0.f, 0.f};
        for (int ki = 0; ki < 4; ki++)
          a = __builtin_amdgcn_mfma_f32_16x16x32_bf16(kf[ki], qf[qb][ki], a, 0, 0, 0);
        s[kb][qb] = a;
      }
      __builtin_amdgcn_s_setprio(0);
    }

    bar_sync();  // BARRIER_A: all waves' K reads done
    if (kt < 15) stageK(kt + 1);  // in flight until BARRIER_END

    // online softmax per q (q = qb*16 + l16); scores pre-scaled by C*log2e.
    bf16x8 pf[2][4];
    float alch[2];
    for (int qb = 0; qb < 2; qb++) {
      float mk[8];
#pragma unroll
      for (int kb = 0; kb < 8; kb++)
        mk[kb] = fmaxf(fmaxf(s[kb][qb][0], s[kb][qb][1]),
                       fmaxf(s[kb][qb][2], s[kb][qb][3]));
      float mx = fmaxf(fmaxf(fmaxf(mk[0], mk[1]), fmaxf(mk[2], mk[3])),
                       fmaxf(fmaxf(mk[4], mk[5]), fmaxf(mk[6], mk[7])));
      mx = fmaxf(mx, __shfl_xor(mx, 16, 64));
      mx = fmaxf(mx, __shfl_xor(mx, 32, 64));
      float mn = m_[qb], al = 1.0f;
      if (!__all(mx <= m_[qb] + 8.0f)) {
        mn = fmaxf(m_[qb], mx);
        al = exp2f(m_[qb] - mn);
        m_[qb] = mn;
      }
      alch[qb] = al;
      uint2 u[8];
      float rs = 0.f;
#pragma unroll
      for (int kb = 0; kb < 8; kb++) {
        float p0 = exp2f(s[kb][qb][0] - mn), p1 = exp2f(s[kb][qb][1] - mn);
        float p2 = exp2f(s[kb][qb][2] - mn), p3 = exp2f(s[kb][qb][3] - mn);
        u[kb] = pack4(p0, p1, p2, p3);
        rs += (p0 + p1) + (p2 + p3);
      }
      rs += __shfl_xor(rs, 16, 64);
      rs += __shfl_xor(rs, 32, 64);
      l_[qb] = l_[qb] * al + rs;
      // exchange: pf[qb][ki] = P[q=l16-row][keys ki*32 + quad*8 + 0..7].
      const bool qo = (quad & 1) != 0;
#pragma unroll
      for (int ki = 0; ki < 4; ki++) {
        u32x2 r1 = __builtin_amdgcn_permlane32_swap(u[2 * ki].x, u[2 * ki + 1].x, false, false);
        u32x2 r2 = __builtin_amdgcn_permlane32_swap(u[2 * ki].y, u[2 * ki + 1].y, false, false);
        uint32_t t1b = (uint32_t)__shfl_xor((int)r1[1], 16, 64);
        uint32_t t1a = (uint32_t)__shfl_xor((int)r1[0], 16, 64);
        uint32_t t2b = (uint32_t)__shfl_xor((int)r2[1], 16, 64);
        uint32_t t2a = (uint32_t)__shfl_xor((int)r2[0], 16, 64);
        uint4 d;
        d.x = qo ? t1b : (uint32_t)r1[0];
        d.y = qo ? t2b : (uint32_t)r2[0];
        d.z = qo ? (uint32_t)r1[1] : t1a;
        d.w = qo ? (uint32_t)r2[1] : t2a;
        pf[qb][ki] = *(bf16x8*)&d;
      }
    }
    if (alch[0] != 1.0f || alch[1] != 1.0f) {
#pragma unroll
      for (int db = 0; db < 8; db++) {
        o[db][0] *= alch[0];
        o[db][1] *= alch[1];
      }
    }

    // BARRIER_B: drain V_kt (8 older loads; the 8 K_{kt+1} stay flying)
    if (kt == 15) asm volatile("s_waitcnt vmcnt(0)" ::: "memory");
    else          asm volatile("s_waitcnt vmcnt(8)" ::: "memory");
    bar_sync();

    // O^T += V^T P^T : A = V-frag (m=d), B = pf (n=q, in registers)
    for (int db = 0; db < 8; db++) {
      bf16x8 vf[4];
      int a0 = (db * 16 + l16) * 128 + ((quad ^ sw) << 3);
      for (int ki = 0; ki < 4; ki++)
        vf[ki] = *(const bf16x8*)&Vls[a0 ^ (ki * 32)];
      __builtin_amdgcn_s_setprio(1);
      for (int qb = 0; qb < 2; qb++)
        for (int ki = 0; ki < 4; ki++)
          o[db][qb] = __builtin_amdgcn_mfma_f32_16x16x32_bf16(vf[ki], pf[qb][ki], o[db][qb], 0, 0, 0);
      __builtin_amdgcn_s_setprio(0);
    }

    // BARRIER_END: K_{kt+1} landed (covered by softmax+PV); Vls free after
    asm volatile("s_waitcnt vmcnt(0)" ::: "memory");
    bar_sync();
  }

  // epilogue: O^T/l -> LDS [q][d] packed b64 -> coalesced global store
  float inv[2] = {1.0f / l_[0], 1.0f / l_[1]};
  for (int qb = 0; qb < 2; qb++) {
    int rq = wave * 32 + qb * 16 + l16;
    for (int db = 0; db < 8; db++) {
      int ch = (db * 2 + (quad >> 1)) ^ sw;
      uint2 pv = pack4(o[db][qb][0] * inv[qb], o[db][qb][1] * inv[qb],
                       o[db][qb][2] * inv[qb], o[db][qb][3] * inv[qb]);
      *(uint2*)&KP[rq * 128 + (ch << 3) + (quad & 1) * 4] = pv;
    }
  }
  __syncthreads();
  u16* Ab = AO + (size_t)(b * 2048 + qt * 128) * 2048 + h * 128;
  for (int i = 0; i < 8; i++) {
    int row = i * 16 + (tid >> 4);
    int seg = tid & 15;
    int pc = seg ^ (row & 7);
    *(uint4*)(Ab + (size_t)row * 2048 + seg * 8) = *(const uint4*)&KP[row * 128 + pc * 8];
  }
}

// ---------------- launch ----------------
extern "C" void kernel_launch(void* const* d_in, const int* in_sizes, int n_in,
                              void* d_out, int out_size, void* d_ws, size_t ws_size,
                              hipStream_t stream) {
  (void)in_sizes; (void)n_in; (void)out_size; (void)ws_size;
  const float* x    = (const float*)d_in[0];
  const float* fcos = (const float*)d_in[1];
  const float* fsin = (const float*)d_in[2];
  const float* wq   = (const float*)d_in[3];
  const float* wk   = (const float*)d_in[4];
  const float* wv   = (const float*)d_in[5];
  const float* wo   = (const float*)d_in[6];

  char* w = (char*)d_ws;
  u16* xb  = (u16*)w;                               // 8192x2048 bf16, reused as attn_out
  u16* wT  = (u16*)(w + 33554432);                  // 3072x2048 bf16
  u16* woT = (u16*)(w + 33554432 + 12582912);       // 2048x2048 bf16
  u16* QKV = (u16*)(w + 33554432 + 12582912 + 8388608);            // 8192x3072 bf16
  u16* Vt  = (u16*)(w + 33554432 + 12582912 + 8388608 + 50331648); // 16x128x2048 bf16
  u16* AO  = xb;

  const float C = 0.08838834764831845f * 1.44269504088896340f;  // 1/sqrt(128)*log2(e)

  cast_x_kernel<<<16384, 256, 0, stream>>>((const float4*)x, (ushort4*)xb);
  wtrans_kernel<<<dim3(64, 64), dim3(32, 8), 0, stream>>>(wq, wT, 2048, 2048, C);
  wtrans_kernel<<<dim3(16, 64), dim3(32, 8), 0, stream>>>(wk, wT + (size_t)2048 * 2048, 2048, 512, 1.0f);
  wtrans_kernel<<<dim3(16, 64), dim3(32, 8), 0, stream>>>(wv, wT + (size_t)2560 * 2048, 2048, 512, 1.0f);
  wtrans_kernel<<<dim3(64, 64), dim3(32, 8), 0, stream>>>(wo, woT, 2048, 2048, 1.0f);

  // GEMM1 (256^2 8-phase) with fused RoPE epilogue; V plain -> vtrans
  gemm_bt_kernel<true><<<dim3(12, 32), 512, 0, stream>>>(xb, wT, QKV, 2048, 3072,
                                                         fcos, fsin);
  vtrans_kernel<<<dim3(64, 4, 16), dim3(32, 8), 0, stream>>>(QKV, Vt);
  attn_kernel<<<dim3(16, 16, 4), 256, 0, stream>>>(QKV, Vt, AO);
  gemm_bt_kernel<false><<<dim3(8, 32), 512, 0, stream>>>(AO, woT, (float*)d_out, 2048, 2048,
                                                         nullptr, nullptr);
}